// Round 9
// baseline (137.611 us; speedup 1.0000x reference)
//
#include <hip/hip_runtime.h>
#include <hip/hip_bf16.h>
#include <math.h>

namespace {
constexpr int B_ = 16, C_ = 256, L_ = 1024, NH_ = 8, DH_ = 32;

typedef __attribute__((ext_vector_type(8))) short short8v;   // 8 bf16
typedef __attribute__((ext_vector_type(4))) float float4v;   // 4 fp32

// fp32 -> bf16 RNE
__device__ __forceinline__ short f2bf(float f) {
    unsigned u = __builtin_bit_cast(unsigned, f);
    u += 0x7fffu + ((u >> 16) & 1u);
    return (short)(u >> 16);
}
// packed fp32x2 -> bf16x2 (v_cvt_pk_bf16_f32 on gfx950), a in low half
__device__ __forceinline__ unsigned pkrn(float a, float b) {
    float2 f; f.x = a; f.y = b;
    __hip_bfloat162 h = __float22bfloat162_rn(f);
    unsigned u;
    __builtin_memcpy(&u, &h, sizeof(u));
    return u;
}
// async global->LDS, 16B per lane; LDS dest is wave-base + lane*16 (forced)
__device__ __forceinline__ void gld16(const short* g, short* l) {
    __builtin_amdgcn_global_load_lds(
        (const __attribute__((address_space(1))) unsigned*)g,
        (__attribute__((address_space(3))) unsigned*)l, 16, 0, 0);
}

// ---------------------------------------------------------------------------
// Weight stack (R4-proven): WA [768][256] bf16 rows {q,k,v}; WoA [256][256].
// R7 lesson: fused fp32-weight staging in the GEMMs is a ~5us pessimization
// (sync loads stall each k-step); bf16 pre-pass + gld16 A-staging wins.
// ---------------------------------------------------------------------------
__global__ __launch_bounds__(256) void prepw_kernel(
    const float* __restrict__ wq, const float* __restrict__ wk,
    const float* __restrict__ wv, const float* __restrict__ wo,
    short* __restrict__ WA, short* __restrict__ WoA)
{
    const int g4 = blockIdx.x * 256 + threadIdx.x;   // 65536 quads
    const int o = g4 >> 6, cc = (g4 & 63) * 4;       // row 0..1023, col quad
    const float* src = (o < 256) ? wq : (o < 512) ? wk : (o < 768) ? wv : wo;
    const float4 v = *(const float4*)&src[(size_t)(o & 255) * 256 + cc];
    short4 s;
    s.x = f2bf(v.x); s.y = f2bf(v.y); s.z = f2bf(v.z); s.w = f2bf(v.w);
    short* dst = (o < 768) ? &WA[(size_t)o * 256 + cc]
                           : &WoA[(size_t)(o - 768) * 256 + cc];
    *(short4*)dst = s;
}

// ---------------------------------------------------------------------------
// QKV GEMM: 256-outch x 64-L tiles (typ = blockIdx.y in {q,k,v}), 768 blocks
// = 3/CU (launch_bounds(256,3); LDS 40KB). A via gld16 (seg-swizzle), B = x
// fp32 transposed+cvt during staging (R4-proven).
// NEW (R9): q/k epilogue goes through an LDS transpose [64][264] so global
// stores are fully coalesced 64B runs (consecutive threads -> consecutive l
// per head). The old direct path was 8B/lane at 64B stride = 64 cache lines
// per wave-store. Values bit-identical (same f2bf of same acc+bias).
// ---------------------------------------------------------------------------
__global__ __launch_bounds__(256, 3) void qkv_kernel(
    const float* __restrict__ X, const short* __restrict__ WA,
    const float* __restrict__ bias0, const float* __restrict__ bias1, const float* __restrict__ bias2,
    float qscale, short* __restrict__ out0, short* __restrict__ out1, short* __restrict__ out2)
{
    const int lt = blockIdx.x, typ = blockIdx.y, b = blockIdx.z;
    const int t = threadIdx.x, wv = t >> 6, lane = t & 63;
    const int quad = lane >> 4, c = lane & 15;
    const int wo = (wv & 1) * 128;       // wave out-channel base (0/128)
    const int wl = (wv >> 1) * 32;       // wave L base (0/32)

    __shared__ short smem[20480];        // 40 KB: sA 32KB | sB 8KB; sT overlay
    short* sA = smem;                    // [256 outch][64 k], swizzled segs
    short* sB = smem + 16384;            // [64 l][64 k]

    float4v acc[8][2];
#pragma unroll
    for (int i = 0; i < 8; ++i)
#pragma unroll
        for (int j = 0; j < 2; ++j) acc[i][j] = (float4v)0.f;

    const short* Arow = WA + (size_t)(typ * 256) * 256;
    const int srow = t >> 3, sseg = t & 7;
    const int seg = sseg ^ (srow & 7);              // source-side swizzle

    for (int kk = 0; kk < 4; ++kk) {
        __syncthreads();
        // A: 256 rows x 64 k bf16 = 32 KB -> 8 gld16 issues
#pragma unroll
        for (int e = 0; e < 8; ++e)
            gld16(Arow + (size_t)(e * 32 + srow) * 256 + kk * 64 + seg * 8,
                  &sA[(e * 256 + t) * 8]);
        // B: x [b][c][l] -> sB [l][seg-swizzled c], lane = l (coalesced)
        {
            const int lrow = t & 63, w8 = t >> 6;   // w8 owns segs 2w8, 2w8+1
            const float* xcol = X + ((size_t)b * C_ + kk * 64 + w8 * 16) * L_ + lt * 64 + lrow;
            float vvv[16];
#pragma unroll
            for (int j = 0; j < 16; ++j) vvv[j] = xcol[(size_t)j * L_];
            unsigned pk[8];
#pragma unroll
            for (int j = 0; j < 8; ++j) pk[j] = pkrn(vvv[2 * j], vvv[2 * j + 1]);
            *(uint4*)&sB[(lrow * 8 + ((2 * w8)     ^ (lrow & 7))) * 8] = *(uint4*)&pk[0];
            *(uint4*)&sB[(lrow * 8 + ((2 * w8 + 1) ^ (lrow & 7))) * 8] = *(uint4*)&pk[4];
        }
        __syncthreads();

#pragma unroll
        for (int kc2 = 0; kc2 < 2; ++kc2) {
            short8v bf[2];
#pragma unroll
            for (int j = 0; j < 2; ++j) {
                const int row = wl + 16 * j + c;
                bf[j] = *(const short8v*)&sB[row * 64 + (((kc2 * 4 + quad) ^ (c & 7)) * 8)];
            }
            // A rows in halves of 4 to cap live af registers
#pragma unroll
            for (int half = 0; half < 2; ++half) {
                short8v af[4];
#pragma unroll
                for (int i2 = 0; i2 < 4; ++i2) {
                    const int row = wo + (half * 4 + i2) * 16 + c;
                    af[i2] = *(const short8v*)&sA[row * 64 + (((kc2 * 4 + quad) ^ (c & 7)) * 8)];
                }
#pragma unroll
                for (int i2 = 0; i2 < 4; ++i2)
#pragma unroll
                    for (int j = 0; j < 2; ++j)
                        acc[half * 4 + i2][j] = __builtin_amdgcn_mfma_f32_16x16x32_bf16(
                            af[i2], bf[j], acc[half * 4 + i2][j], 0, 0, 0);
            }
        }
    }

    const float* bp = (typ == 0) ? bias0 : (typ == 1) ? bias1 : bias2;
    const float sc = (typ == 0) ? qscale : 1.f;
    short* outp = (typ == 0) ? out0 : (typ == 1) ? out1 : out2;
    if (typ < 2) {
        // LDS-transpose epilogue: sT [64 l][264 ch-padded] (33.8 KB <= 40 KB)
        __syncthreads();                     // all MFMA reads of sA/sB done
        short* sT = smem;
#pragma unroll
        for (int i = 0; i < 8; ++i) {
            const int ch0 = wo + 16 * i + quad * 4;
            float bias[4];
#pragma unroll
            for (int r = 0; r < 4; ++r) bias[r] = bp[ch0 + r];
#pragma unroll
            for (int j = 0; j < 2; ++j) {
                short4 sv;
                sv.x = f2bf((acc[i][j][0] + bias[0]) * sc);
                sv.y = f2bf((acc[i][j][1] + bias[1]) * sc);
                sv.z = f2bf((acc[i][j][2] + bias[2]) * sc);
                sv.w = f2bf((acc[i][j][3] + bias[3]) * sc);
                *(short4*)&sT[(wl + 16 * j + c) * 264 + ch0] = sv;
            }
        }
        __syncthreads();
        // 512 units of 64B: unit u = h*64 + l; consecutive threads ->
        // consecutive l for fixed head -> contiguous 4KB per 64-thread group
#pragma unroll
        for (int k = 0; k < 2; ++k) {
            const int u = k * 256 + t;
            const int h = u >> 6, l = u & 63;
            const short* src = &sT[l * 264 + h * 32];
            short* dst = &outp[(((size_t)b * NH_ + h) * L_ + lt * 64 + l) * 32];
            *(uint4*)&dst[0]  = *(const uint4*)&src[0];
            *(uint4*)&dst[8]  = *(const uint4*)&src[8];
            *(uint4*)&dst[16] = *(const uint4*)&src[16];
            *(uint4*)&dst[24] = *(const uint4*)&src[24];
        }
    } else {
        // v: [b][c][l] — lanes already stride l contiguously (32B segments)
#pragma unroll
        for (int i = 0; i < 8; ++i)
#pragma unroll
            for (int r = 0; r < 4; ++r) {
                const int ch = wo + 16 * i + quad * 4 + r;
                const float bias = bp[ch];
#pragma unroll
                for (int j = 0; j < 2; ++j)
                    outp[((size_t)b * C_ + ch) * L_ + lt * 64 + wl + 16 * j + c] =
                        f2bf(acc[i][j][r] + bias);
            }
    }
}

// ---------------------------------------------------------------------------
// O-projection GEMM: 128-outch x 32-L tiles (R9: was 64-L). Grid 1024 blocks
// = 4/CU (launch_bounds(256,4); LDS 20 KB) — R3 mechanism: more resident
// blocks hide per-block barrier drains. A = WoA bf16 via gld16, B = athi
// bf16 via gld16. Epilogue: fp32 out + bias (64B quad segments, adequate).
// ---------------------------------------------------------------------------
__global__ __launch_bounds__(256, 4) void ogemm_kernel(
    const short* __restrict__ WoA,
    const short* __restrict__ Bsrc,   // athi [b][l][c] bf16
    const float* __restrict__ bias,
    float* __restrict__ out)
{
    const int lt = blockIdx.x, ot = blockIdx.y, b = blockIdx.z;
    const int t = threadIdx.x, wv = t >> 6, lane = t & 63;
    const int quad = lane >> 4, c = lane & 15;
    const int wo = (wv & 1) * 64;
    const int wl = (wv >> 1) * 16;       // wave L base (0/16)

    __shared__ short sA[128 * 64];   // 16 KB
    __shared__ short sB[32 * 64];    // 4 KB

    float4v acc[4];
#pragma unroll
    for (int i = 0; i < 4; ++i) acc[i] = (float4v)0.f;

    const short* Arow = WoA + (size_t)(ot * 128) * 256;
    const int srow = t >> 3, sseg = t & 7;
    const int seg = sseg ^ (srow & 7);

    for (int kk = 0; kk < 4; ++kk) {
        __syncthreads();
#pragma unroll
        for (int e = 0; e < 4; ++e)
            gld16(Arow + (size_t)(e * 32 + srow) * 256 + kk * 64 + seg * 8,
                  &sA[(e * 256 + t) * 8]);
        gld16(Bsrc + ((size_t)b * L_ + lt * 32 + srow) * 256 + kk * 64 + seg * 8,
              &sB[t * 8]);
        __syncthreads();

#pragma unroll
        for (int kc2 = 0; kc2 < 2; ++kc2) {
            short8v af[4], bf;
#pragma unroll
            for (int i = 0; i < 4; ++i) {
                const int row = wo + 16 * i + c;
                af[i] = *(const short8v*)&sA[row * 64 + (((kc2 * 4 + quad) ^ (c & 7)) * 8)];
            }
            {
                const int row = wl + c;
                bf = *(const short8v*)&sB[row * 64 + (((kc2 * 4 + quad) ^ (c & 7)) * 8)];
            }
#pragma unroll
            for (int i = 0; i < 4; ++i)
                acc[i] = __builtin_amdgcn_mfma_f32_16x16x32_bf16(af[i], bf, acc[i], 0, 0, 0);
        }
    }

#pragma unroll
    for (int i = 0; i < 4; ++i)
#pragma unroll
        for (int r = 0; r < 4; ++r) {
            const int ch = ot * 128 + wo + 16 * i + quad * 4 + r;
            out[((size_t)b * C_ + ch) * L_ + lt * 32 + wl + c] = acc[i][r] + bias[ch];
        }
}

// ---------------------------------------------------------------------------
// MFMA flash attention v4 + R9 epilogue.
//  - K/V double-buffered in LDS, ONE barrier per tile; i+1 stage issued right
//    after the barrier, drained at the NEXT tile's barrier (overlapped).
//  - sPT single-buffered (wave-private; same-wave DS ordering).
//  - sK/sV XOR-swizzled (linear gld_lds dest + pre-swizzled GLOBAL source,
//    same XOR on the read) — conflict-free kf/vf ds_read_b128.
//  - no setprio (4-wave barrier-locked blocks = m190 lockstep regime).
//  - NEW: athi store goes through the wave's own (idle) sPT slice [32][40]
//    (wave-private -> no barrier): 2x16B aligned stores/lane vs 4x8B scatter.
// ---------------------------------------------------------------------------
__global__ __launch_bounds__(256, 4) void attn_kernel(
    const short* __restrict__ qt,   // [b][h][l][d] bf16 (scale*log2e folded)
    const short* __restrict__ kt,   // [b][h][l][d] bf16
    const short* __restrict__ vb,   // [b][c][l]    bf16
    short* __restrict__ athi)       // [b][l][c]    bf16
{
    const int flat = blockIdx.x;
    const int g = ((flat >> 6) << 3) | (flat & 7);  // (b,h) group -> one XCD
    const int chunk = (flat >> 3) & 7;
    const int b = g >> 3, h = g & 7;
    const int t = threadIdx.x;
    const int wv = t >> 6, lane = t & 63;
    const int quad = lane >> 4, c = lane & 15;
    const int lq0 = chunk * 128 + wv * 32;          // wave's 32 queries

    __shared__ __align__(16) short sK[2][64 * 32];        // 8 KB, double-buffered
    __shared__ __align__(16) short sV[2][2][32 * 32];     // 8 KB, double-buffered
    __shared__ __align__(16) short sPT[4][2][16][64];     // 16 KB, wave-private

    const size_t bh = (size_t)b * NH_ + h;
    const short* qbase = qt + (bh * L_) * 32;
    const short* kbase = kt + (bh * L_) * 32;
    const size_t vrow = (size_t)b * C_ + h * DH_;

    short8v qfrag[2];
#pragma unroll
    for (int qf = 0; qf < 2; ++qf)
        qfrag[qf] = *(const short8v*)(qbase + (size_t)(lq0 + qf * 16 + c) * 32 + quad * 8);

    float lp4[2][4];
#pragma unroll
    for (int qf = 0; qf < 2; ++qf)
#pragma unroll
        for (int r = 0; r < 4; ++r) lp4[qf][r] = 0.f;
    float4v o_acc[2][2];
#pragma unroll
    for (int qf = 0; qf < 2; ++qf) { o_acc[qf][0] = (float4v)0.f; o_acc[qf][1] = (float4v)0.f; }

    // Pre-swizzled source segment: LDS stays linear (gld_lds requirement),
    // global source carries the involution seg ^ ((row>>1)&3).
    const int sseg = (t & 3) ^ ((t >> 3) & 3);
    // Read-side XOR (row = kb*16+c or nb2*16+c; (row>>1)&3 == (c>>1)&3).
    const int rsw = (c >> 1) & 3;

    auto stage = [&](int m0, int buf) {
        gld16(kbase + (size_t)(m0 + (t >> 2)) * 32 + sseg * 8, &sK[buf][t * 8]);
        gld16(vb + (vrow + ((t >> 2) & 31)) * L_ + m0 + (t >> 7) * 32 + sseg * 8,
              (short*)sV[buf] + t * 8);
    };

    stage(0, 0);

    short8v vfp[2][2];

    for (int i = 0; i <= 16; ++i) {                // ROLLED — do not unroll
        short8v kf[4], vf[2][2];
        if (i < 16) {
            __syncthreads();                 // stage(i) visible (vmcnt+lgkm drained)
            if (i < 15) stage((i + 1) * 64, (i + 1) & 1);   // prefetch, other buffer
            const short* Kb = sK[i & 1];
            const short* Vb = (const short*)sV[i & 1];
#pragma unroll
            for (int kb = 0; kb < 4; ++kb)
                kf[kb] = *(const short8v*)&Kb[(kb * 16 + c) * 32 + ((quad ^ rsw) * 8)];
#pragma unroll
            for (int kc = 0; kc < 2; ++kc)
#pragma unroll
                for (int nb2 = 0; nb2 < 2; ++nb2)
                    vf[kc][nb2] = *(const short8v*)&Vb[kc * 1024 + (nb2 * 16 + c) * 32 + ((quad ^ rsw) * 8)];
        }

        // PV for tile i-1: sPT reads hit same-wave writes from the previous
        // iteration (same-wave DS ordering; no barrier needed)
        if (i > 0) {
#pragma unroll
            for (int qf = 0; qf < 2; ++qf)
#pragma unroll
                for (int kc = 0; kc < 2; ++kc) {
                    const int G = (kc * 4 + quad) ^ (c & 7);
                    const short8v pf = *(const short8v*)&sPT[wv][qf][c][G * 8];
#pragma unroll
                    for (int nb2 = 0; nb2 < 2; ++nb2)
                        o_acc[qf][nb2] = __builtin_amdgcn_mfma_f32_16x16x32_bf16(vfp[kc][nb2], pf, o_acc[qf][nb2], 0, 0, 0);
                }
        }

        // S/exp/pack/write for tile i (overwrite is after this wave's PV reads
        // in program order -> safe single buffer)
        if (i < 16) {
            float4v st[2][4];
#pragma unroll
            for (int qf = 0; qf < 2; ++qf)
#pragma unroll
                for (int kb = 0; kb < 4; ++kb)
                    st[qf][kb] = __builtin_amdgcn_mfma_f32_16x16x32_bf16(kf[kb], qfrag[qf], (float4v)0.f, 0, 0, 0);
#pragma unroll
            for (int qf = 0; qf < 2; ++qf)
#pragma unroll
                for (int kb = 0; kb < 4; ++kb) {
                    float p[4];
#pragma unroll
                    for (int r = 0; r < 4; ++r) {
                        p[r] = __builtin_amdgcn_exp2f(st[qf][kb][r]);
                        lp4[qf][r] += p[r];
                    }
                    uint2 w;
                    w.x = pkrn(p[0], p[1]);
                    w.y = pkrn(p[2], p[3]);
                    const int Gw = (kb * 2 + (quad >> 1)) ^ (c & 7);
                    *(uint2*)&sPT[wv][qf][c][Gw * 8 + (quad & 1) * 4] = w;
                }
#pragma unroll
            for (int kc = 0; kc < 2; ++kc)
#pragma unroll
                for (int nb2 = 0; nb2 < 2; ++nb2) vfp[kc][nb2] = vf[kc][nb2];
        }
    }

    // Epilogue: per-wave LDS transpose through own sPT slice (wave-private,
    // PV of tile 15 already read it -> program order, no barrier).
    short* sW = (short*)&sPT[wv][0][0][0];          // use [32][40] (2.5 KB)
#pragma unroll
    for (int qf = 0; qf < 2; ++qf) {
        float l = (lp4[qf][0] + lp4[qf][1]) + (lp4[qf][2] + lp4[qf][3]);
        l += __shfl_xor(l, 16);
        l += __shfl_xor(l, 32);
        const float inv = 1.f / l;
#pragma unroll
        for (int nb2 = 0; nb2 < 2; ++nb2) {
            short4 sv;
            sv.x = f2bf(o_acc[qf][nb2][0] * inv);
            sv.y = f2bf(o_acc[qf][nb2][1] * inv);
            sv.z = f2bf(o_acc[qf][nb2][2] * inv);
            sv.w = f2bf(o_acc[qf][nb2][3] * inv);
            *(short4*)&sW[(qf * 16 + c) * 40 + nb2 * 16 + quad * 4] = sv;
        }
    }
    {
        const int lq = lane & 31, hf = lane >> 5;   // lane -> (l, 16d-half)
        const short* src = &sW[lq * 40 + hf * 16];  // 80B row stride: 16B-aligned
        short* dst = &athi[((size_t)b * L_ + lq0 + lq) * C_ + h * DH_ + hf * 16];
        *(uint4*)&dst[0] = *(const uint4*)&src[0];
        *(uint4*)&dst[8] = *(const uint4*)&src[8];
    }
}

}  // namespace

extern "C" void kernel_launch(void* const* d_in, const int* in_sizes, int n_in,
                              void* d_out, int out_size, void* d_ws, size_t ws_size,
                              hipStream_t stream) {
    const float* x   = (const float*)d_in[0];
    const float* w_q = (const float*)d_in[1];
    const float* b_q = (const float*)d_in[2];
    const float* w_k = (const float*)d_in[3];
    const float* b_k = (const float*)d_in[4];
    const float* w_v = (const float*)d_in[5];
    const float* b_v = (const float*)d_in[6];
    const float* w_o = (const float*)d_in[7];
    const float* b_o = (const float*)d_in[8];
    float* out = (float*)d_out;

    const size_t NT = (size_t)B_ * L_ * C_;   // 4,194,304
    short* WA   = (short*)d_ws;               // 768*256 bf16
    short* WoA  = WA + 768 * 256;             // 256*256 bf16
    short* qt   = WoA + 256 * 256;
    short* kt   = qt + NT;
    short* vb   = kt + NT;
    short* athi = vb + NT;

    const float scale_q = 0.17677669529663687f * 1.4426950408889634f; // 1/sqrt(32)*log2(e)

    prepw_kernel<<<dim3(256), 256, 0, stream>>>(w_q, w_k, w_v, w_o, WA, WoA);
    qkv_kernel<<<dim3(L_ / 64, 3, B_), 256, 0, stream>>>(
        x, WA, b_q, b_k, b_v, scale_q, qt, kt, vb);
    attn_kernel<<<dim3(1024), 256, 0, stream>>>(qt, kt, vb, athi);
    ogemm_kernel<<<dim3(L_ / 32, 2, B_), 256, 0, stream>>>(
        WoA, athi, b_o, out);
}

// Round 12
// 133.889 us; speedup vs baseline: 1.0278x; 1.0278x over previous
//
#include <hip/hip_runtime.h>
#include <hip/hip_bf16.h>
#include <math.h>

namespace {
constexpr int B_ = 16, C_ = 256, L_ = 1024, NH_ = 8, DH_ = 32;

typedef __attribute__((ext_vector_type(8))) short short8v;   // 8 bf16
typedef __attribute__((ext_vector_type(4))) float float4v;   // 4 fp32

// fp32 -> bf16 RNE
__device__ __forceinline__ short f2bf(float f) {
    unsigned u = __builtin_bit_cast(unsigned, f);
    u += 0x7fffu + ((u >> 16) & 1u);
    return (short)(u >> 16);
}
// packed fp32x2 -> bf16x2 (v_cvt_pk_bf16_f32 on gfx950), a in low half
__device__ __forceinline__ unsigned pkrn(float a, float b) {
    float2 f; f.x = a; f.y = b;
    __hip_bfloat162 h = __float22bfloat162_rn(f);
    unsigned u;
    __builtin_memcpy(&u, &h, sizeof(u));
    return u;
}
// async global->LDS, 16B per lane; LDS dest is wave-base + lane*16 (forced)
__device__ __forceinline__ void gld16(const short* g, short* l) {
    __builtin_amdgcn_global_load_lds(
        (const __attribute__((address_space(1))) unsigned*)g,
        (__attribute__((address_space(3))) unsigned*)l, 16, 0, 0);
}

// ---------------------------------------------------------------------------
// Weight stack (R4-proven): WA [768][256] bf16 rows {q,k,v}; WoA [256][256].
// R7 lesson: fused fp32-weight staging in the GEMMs is a ~5us pessimization
// (sync loads stall each k-step); bf16 pre-pass + gld16 A-staging wins.
// ---------------------------------------------------------------------------
__global__ __launch_bounds__(256) void prepw_kernel(
    const float* __restrict__ wq, const float* __restrict__ wk,
    const float* __restrict__ wv, const float* __restrict__ wo,
    short* __restrict__ WA, short* __restrict__ WoA)
{
    const int g4 = blockIdx.x * 256 + threadIdx.x;   // 65536 quads
    const int o = g4 >> 6, cc = (g4 & 63) * 4;       // row 0..1023, col quad
    const float* src = (o < 256) ? wq : (o < 512) ? wk : (o < 768) ? wv : wo;
    const float4 v = *(const float4*)&src[(size_t)(o & 255) * 256 + cc];
    short4 s;
    s.x = f2bf(v.x); s.y = f2bf(v.y); s.z = f2bf(v.z); s.w = f2bf(v.w);
    short* dst = (o < 768) ? &WA[(size_t)o * 256 + cc]
                           : &WoA[(size_t)(o - 768) * 256 + cc];
    *(short4*)dst = s;
}

// ---------------------------------------------------------------------------
// QKV GEMM v2: 256-outch x 64-L tiles (typ = blockIdx.y in {q,k,v}).
// Grid 768 blocks = EXACTLY 3/CU single-pass (launch_bounds(256,3); LDS 40KB).
// vs R4's 1536-block 128-outch version: half the per-block overhead instances
// (prologue/9 barriers/epilogue) and the fused x-transpose conversion runs
// 3x per x-tile instead of 6x (total conversion VALU halves). Same MFMA
// work; accumulation order per output element unchanged -> bit-identical.
//  - A: WA bf16 via gld16, seg-swizzle invariant (slot s of row r holds
//    source seg s^(r&7)).
//  - B: x [b][c][l] fp32 transposed+cvt during staging (lane=l coalesced,
//    R4-proven). Blocks sharing an x-tile (same lt,b) differ by 16 in linear
//    id -> same XCD L2 serves the repeat reads.
// NOTE (R10/R11 post-mortem): the double-buffered single-barrier variant of
// this k-loop failed 4 consecutive container attempts — left as 2-barrier
// single-buffer (this exact source measured 135.0 us, passed).
// ---------------------------------------------------------------------------
__global__ __launch_bounds__(256, 3) void qkv_kernel(
    const float* __restrict__ X, const short* __restrict__ WA,
    const float* __restrict__ bias0, const float* __restrict__ bias1, const float* __restrict__ bias2,
    float qscale, short* __restrict__ out0, short* __restrict__ out1, short* __restrict__ out2)
{
    const int lt = blockIdx.x, typ = blockIdx.y, b = blockIdx.z;
    const int t = threadIdx.x, wv = t >> 6, lane = t & 63;
    const int quad = lane >> 4, c = lane & 15;
    const int wo = (wv & 1) * 128;       // wave out-channel base (0/128)
    const int wl = (wv >> 1) * 32;       // wave L base (0/32)

    __shared__ short sA[256 * 64];   // [outch][k64], swizzled segments (32 KB)
    __shared__ short sB[64 * 64];    // [l][k64] (8 KB)

    float4v acc[8][2];
#pragma unroll
    for (int i = 0; i < 8; ++i)
#pragma unroll
        for (int j = 0; j < 2; ++j) acc[i][j] = (float4v)0.f;

    const short* Arow = WA + (size_t)(typ * 256) * 256;
    const int srow = t >> 3, sseg = t & 7;
    const int seg = sseg ^ (srow & 7);              // source-side swizzle

    for (int kk = 0; kk < 4; ++kk) {
        __syncthreads();
        // A: 256 rows x 64 k bf16 = 32 KB -> 8 gld16 issues
#pragma unroll
        for (int e = 0; e < 8; ++e)
            gld16(Arow + (size_t)(e * 32 + srow) * 256 + kk * 64 + seg * 8,
                  &sA[(e * 256 + t) * 8]);
        // B: x [b][c][l] -> sB [l][seg-swizzled c], lane = l (coalesced)
        {
            const int lrow = t & 63, w8 = t >> 6;   // w8 owns segs 2w8, 2w8+1
            const float* xcol = X + ((size_t)b * C_ + kk * 64 + w8 * 16) * L_ + lt * 64 + lrow;
            float vvv[16];
#pragma unroll
            for (int j = 0; j < 16; ++j) vvv[j] = xcol[(size_t)j * L_];
            unsigned pk[8];
#pragma unroll
            for (int j = 0; j < 8; ++j) pk[j] = pkrn(vvv[2 * j], vvv[2 * j + 1]);
            *(uint4*)&sB[(lrow * 8 + ((2 * w8)     ^ (lrow & 7))) * 8] = *(uint4*)&pk[0];
            *(uint4*)&sB[(lrow * 8 + ((2 * w8 + 1) ^ (lrow & 7))) * 8] = *(uint4*)&pk[4];
        }
        __syncthreads();

#pragma unroll
        for (int kc2 = 0; kc2 < 2; ++kc2) {
            short8v bf[2];
#pragma unroll
            for (int j = 0; j < 2; ++j) {
                const int row = wl + 16 * j + c;
                bf[j] = *(const short8v*)&sB[row * 64 + (((kc2 * 4 + quad) ^ (c & 7)) * 8)];
            }
            // A rows in halves of 4 to cap live af registers
#pragma unroll
            for (int half = 0; half < 2; ++half) {
                short8v af[4];
#pragma unroll
                for (int i2 = 0; i2 < 4; ++i2) {
                    const int row = wo + (half * 4 + i2) * 16 + c;
                    af[i2] = *(const short8v*)&sA[row * 64 + (((kc2 * 4 + quad) ^ (c & 7)) * 8)];
                }
#pragma unroll
                for (int i2 = 0; i2 < 4; ++i2)
#pragma unroll
                    for (int j = 0; j < 2; ++j)
                        acc[half * 4 + i2][j] = __builtin_amdgcn_mfma_f32_16x16x32_bf16(
                            af[i2], bf[j], acc[half * 4 + i2][j], 0, 0, 0);
            }
        }
    }

    const float* bp = (typ == 0) ? bias0 : (typ == 1) ? bias1 : bias2;
    const float sc = (typ == 0) ? qscale : 1.f;
    short* outp = (typ == 0) ? out0 : (typ == 1) ? out1 : out2;
    if (typ < 2) {
#pragma unroll
        for (int i = 0; i < 8; ++i) {
            const int ch0 = wo + 16 * i + quad * 4;
            const int head = ch0 >> 5, d0 = ch0 & 31;
            float bias[4];
#pragma unroll
            for (int r = 0; r < 4; ++r) bias[r] = bp[ch0 + r];
#pragma unroll
            for (int j = 0; j < 2; ++j) {
                const int l = lt * 64 + wl + 16 * j + c;
                short4 sv;
                sv.x = f2bf((acc[i][j][0] + bias[0]) * sc);
                sv.y = f2bf((acc[i][j][1] + bias[1]) * sc);
                sv.z = f2bf((acc[i][j][2] + bias[2]) * sc);
                sv.w = f2bf((acc[i][j][3] + bias[3]) * sc);
                *(short4*)&outp[(((size_t)b * NH_ + head) * L_ + l) * 32 + d0] = sv;
            }
        }
    } else {
#pragma unroll
        for (int i = 0; i < 8; ++i)
#pragma unroll
            for (int r = 0; r < 4; ++r) {
                const int ch = wo + 16 * i + quad * 4 + r;
                const float bias = bp[ch];
#pragma unroll
                for (int j = 0; j < 2; ++j)
                    outp[((size_t)b * C_ + ch) * L_ + lt * 64 + wl + 16 * j + c] =
                        f2bf(acc[i][j][r] + bias);
            }
    }
}

// ---------------------------------------------------------------------------
// O-projection GEMM (R4-proven): 128-outch x 64-L tiles, KTOT=256, A = WoA
// bf16 via gld16, B = athi bf16 via gld16. Grid 512 blocks (2/CU), LDS 24 KB.
// ---------------------------------------------------------------------------
__global__ __launch_bounds__(256, 4) void ogemm_kernel(
    const short* __restrict__ WoA,
    const short* __restrict__ Bsrc,   // athi [b][l][c] bf16
    const float* __restrict__ bias,
    float* __restrict__ out)
{
    const int lt = blockIdx.x, ot = blockIdx.y, b = blockIdx.z;
    const int t = threadIdx.x, wv = t >> 6, lane = t & 63;
    const int quad = lane >> 4, c = lane & 15;
    const int wo = (wv & 1) * 64;
    const int wl = (wv >> 1) * 32;

    __shared__ short sA[128 * 64];
    __shared__ short sB[64 * 64];

    float4v acc[4][2];
#pragma unroll
    for (int i = 0; i < 4; ++i)
#pragma unroll
        for (int j = 0; j < 2; ++j) acc[i][j] = (float4v)0.f;

    const short* Arow = WoA + (size_t)(ot * 128) * 256;
    const int srow = t >> 3, sseg = t & 7;
    const int seg = sseg ^ (srow & 7);

    for (int kk = 0; kk < 4; ++kk) {
        __syncthreads();
#pragma unroll
        for (int e = 0; e < 4; ++e)
            gld16(Arow + (size_t)(e * 32 + srow) * 256 + kk * 64 + seg * 8,
                  &sA[(e * 256 + t) * 8]);
#pragma unroll
        for (int e = 0; e < 2; ++e)
            gld16(Bsrc + ((size_t)b * L_ + lt * 64 + e * 32 + srow) * 256 + kk * 64 + seg * 8,
                  &sB[(e * 256 + t) * 8]);
        __syncthreads();

#pragma unroll
        for (int kc2 = 0; kc2 < 2; ++kc2) {
            short8v af[4], bf[2];
#pragma unroll
            for (int i = 0; i < 4; ++i) {
                const int row = wo + 16 * i + c;
                af[i] = *(const short8v*)&sA[row * 64 + (((kc2 * 4 + quad) ^ (c & 7)) * 8)];
            }
#pragma unroll
            for (int j = 0; j < 2; ++j) {
                const int row = wl + 16 * j + c;
                bf[j] = *(const short8v*)&sB[row * 64 + (((kc2 * 4 + quad) ^ (c & 7)) * 8)];
            }
#pragma unroll
            for (int i = 0; i < 4; ++i)
#pragma unroll
                for (int j = 0; j < 2; ++j)
                    acc[i][j] = __builtin_amdgcn_mfma_f32_16x16x32_bf16(af[i], bf[j], acc[i][j], 0, 0, 0);
        }
    }

#pragma unroll
    for (int i = 0; i < 4; ++i)
#pragma unroll
        for (int r = 0; r < 4; ++r) {
            const int ch = ot * 128 + wo + 16 * i + quad * 4 + r;
            const float bs = bias[ch];
#pragma unroll
            for (int j = 0; j < 2; ++j)
                out[((size_t)b * C_ + ch) * L_ + lt * 64 + wl + 16 * j + c] =
                    acc[i][j][r] + bs;
        }
}

// ---------------------------------------------------------------------------
// MFMA flash attention v4 (R8 exact copy — best measured).
//  - K/V double-buffered in LDS, ONE barrier per tile; i+1 stage issued right
//    after the barrier, drained at the NEXT tile's barrier (overlapped).
//  - sPT single-buffered (wave-private; same-wave DS ordering).
//  - sK/sV XOR-swizzled (linear gld_lds dest + pre-swizzled GLOBAL source,
//    same XOR on the read) — conflict-free kf/vf ds_read_b128.
//  - no setprio (4-wave barrier-locked blocks = m190 lockstep regime).
// ---------------------------------------------------------------------------
__global__ __launch_bounds__(256, 4) void attn_kernel(
    const short* __restrict__ qt,   // [b][h][l][d] bf16 (scale*log2e folded)
    const short* __restrict__ kt,   // [b][h][l][d] bf16
    const short* __restrict__ vb,   // [b][c][l]    bf16
    short* __restrict__ athi)       // [b][l][c]    bf16
{
    const int flat = blockIdx.x;
    const int g = ((flat >> 6) << 3) | (flat & 7);  // (b,h) group -> one XCD
    const int chunk = (flat >> 3) & 7;
    const int b = g >> 3, h = g & 7;
    const int t = threadIdx.x;
    const int wv = t >> 6, lane = t & 63;
    const int quad = lane >> 4, c = lane & 15;
    const int lq0 = chunk * 128 + wv * 32;          // wave's 32 queries

    __shared__ __align__(16) short sK[2][64 * 32];        // 8 KB, double-buffered
    __shared__ __align__(16) short sV[2][2][32 * 32];     // 8 KB, double-buffered
    __shared__ __align__(16) short sPT[4][2][16][64];     // 16 KB, wave-private

    const size_t bh = (size_t)b * NH_ + h;
    const short* qbase = qt + (bh * L_) * 32;
    const short* kbase = kt + (bh * L_) * 32;
    const size_t vrow = (size_t)b * C_ + h * DH_;

    short8v qfrag[2];
#pragma unroll
    for (int qf = 0; qf < 2; ++qf)
        qfrag[qf] = *(const short8v*)(qbase + (size_t)(lq0 + qf * 16 + c) * 32 + quad * 8);

    float lp4[2][4];
#pragma unroll
    for (int qf = 0; qf < 2; ++qf)
#pragma unroll
        for (int r = 0; r < 4; ++r) lp4[qf][r] = 0.f;
    float4v o_acc[2][2];
#pragma unroll
    for (int qf = 0; qf < 2; ++qf) { o_acc[qf][0] = (float4v)0.f; o_acc[qf][1] = (float4v)0.f; }

    // Pre-swizzled source segment: LDS stays linear (gld_lds requirement),
    // global source carries the involution seg ^ ((row>>1)&3).
    const int sseg = (t & 3) ^ ((t >> 3) & 3);
    // Read-side XOR (row = kb*16+c or nb2*16+c; (row>>1)&3 == (c>>1)&3).
    const int rsw = (c >> 1) & 3;

    auto stage = [&](int m0, int buf) {
        gld16(kbase + (size_t)(m0 + (t >> 2)) * 32 + sseg * 8, &sK[buf][t * 8]);
        gld16(vb + (vrow + ((t >> 2) & 31)) * L_ + m0 + (t >> 7) * 32 + sseg * 8,
              (short*)sV[buf] + t * 8);
    };

    stage(0, 0);

    short8v vfp[2][2];

    for (int i = 0; i <= 16; ++i) {                // ROLLED — do not unroll
        short8v kf[4], vf[2][2];
        if (i < 16) {
            __syncthreads();                 // stage(i) visible (vmcnt+lgkm drained)
            if (i < 15) stage((i + 1) * 64, (i + 1) & 1);   // prefetch, other buffer
            const short* Kb = sK[i & 1];
            const short* Vb = (const short*)sV[i & 1];
#pragma unroll
            for (int kb = 0; kb < 4; ++kb)
                kf[kb] = *(const short8v*)&Kb[(kb * 16 + c) * 32 + ((quad ^ rsw) * 8)];
#pragma unroll
            for (int kc = 0; kc < 2; ++kc)
#pragma unroll
                for (int nb2 = 0; nb2 < 2; ++nb2)
                    vf[kc][nb2] = *(const short8v*)&Vb[kc * 1024 + (nb2 * 16 + c) * 32 + ((quad ^ rsw) * 8)];
        }

        // PV for tile i-1: sPT reads hit same-wave writes from the previous
        // iteration (already drained by the loop-top barrier -> no lgkm stall)
        if (i > 0) {
#pragma unroll
            for (int qf = 0; qf < 2; ++qf)
#pragma unroll
                for (int kc = 0; kc < 2; ++kc) {
                    const int G = (kc * 4 + quad) ^ (c & 7);
                    const short8v pf = *(const short8v*)&sPT[wv][qf][c][G * 8];
#pragma unroll
                    for (int nb2 = 0; nb2 < 2; ++nb2)
                        o_acc[qf][nb2] = __builtin_amdgcn_mfma_f32_16x16x32_bf16(vfp[kc][nb2], pf, o_acc[qf][nb2], 0, 0, 0);
                }
        }

        // S/exp/pack/write for tile i (overwrite is after this wave's PV reads
        // in program order -> safe single buffer)
        if (i < 16) {
            float4v st[2][4];
#pragma unroll
            for (int qf = 0; qf < 2; ++qf)
#pragma unroll
                for (int kb = 0; kb < 4; ++kb)
                    st[qf][kb] = __builtin_amdgcn_mfma_f32_16x16x32_bf16(kf[kb], qfrag[qf], (float4v)0.f, 0, 0, 0);
#pragma unroll
            for (int qf = 0; qf < 2; ++qf)
#pragma unroll
                for (int kb = 0; kb < 4; ++kb) {
                    float p[4];
#pragma unroll
                    for (int r = 0; r < 4; ++r) {
                        p[r] = __builtin_amdgcn_exp2f(st[qf][kb][r]);
                        lp4[qf][r] += p[r];
                    }
                    uint2 w;
                    w.x = pkrn(p[0], p[1]);
                    w.y = pkrn(p[2], p[3]);
                    const int Gw = (kb * 2 + (quad >> 1)) ^ (c & 7);
                    *(uint2*)&sPT[wv][qf][c][Gw * 8 + (quad & 1) * 4] = w;
                }
#pragma unroll
            for (int kc = 0; kc < 2; ++kc)
#pragma unroll
                for (int nb2 = 0; nb2 < 2; ++nb2) vfp[kc][nb2] = vf[kc][nb2];
        }
    }

#pragma unroll
    for (int qf = 0; qf < 2; ++qf) {
        float l = (lp4[qf][0] + lp4[qf][1]) + (lp4[qf][2] + lp4[qf][3]);
        l += __shfl_xor(l, 16);
        l += __shfl_xor(l, 32);
        const float inv = 1.f / l;
#pragma unroll
        for (int nb2 = 0; nb2 < 2; ++nb2) {
            short4 sv;
            sv.x = f2bf(o_acc[qf][nb2][0] * inv);
            sv.y = f2bf(o_acc[qf][nb2][1] * inv);
            sv.z = f2bf(o_acc[qf][nb2][2] * inv);
            sv.w = f2bf(o_acc[qf][nb2][3] * inv);
            *(short4*)&athi[((size_t)b * L_ + lq0 + qf * 16 + c) * C_ + h * DH_ + nb2 * 16 + quad * 4] = sv;
        }
    }
}

}  // namespace

extern "C" void kernel_launch(void* const* d_in, const int* in_sizes, int n_in,
                              void* d_out, int out_size, void* d_ws, size_t ws_size,
                              hipStream_t stream) {
    const float* x   = (const float*)d_in[0];
    const float* w_q = (const float*)d_in[1];
    const float* b_q = (const float*)d_in[2];
    const float* w_k = (const float*)d_in[3];
    const float* b_k = (const float*)d_in[4];
    const float* w_v = (const float*)d_in[5];
    const float* b_v = (const float*)d_in[6];
    const float* w_o = (const float*)d_in[7];
    const float* b_o = (const float*)d_in[8];
    float* out = (float*)d_out;

    const size_t NT = (size_t)B_ * L_ * C_;   // 4,194,304
    short* WA   = (short*)d_ws;               // 768*256 bf16
    short* WoA  = WA + 768 * 256;             // 256*256 bf16
    short* qt   = WoA + 256 * 256;
    short* kt   = qt + NT;
    short* vb   = kt + NT;
    short* athi = vb + NT;

    const float scale_q = 0.17677669529663687f * 1.4426950408889634f; // 1/sqrt(32)*log2(e)

    prepw_kernel<<<dim3(256), 256, 0, stream>>>(w_q, w_k, w_v, w_o, WA, WoA);
    qkv_kernel<<<dim3(L_ / 64, 3, B_), 256, 0, stream>>>(
        x, WA, b_q, b_k, b_v, scale_q, qt, kt, vb);
    attn_kernel<<<dim3(1024), 256, 0, stream>>>(qt, kt, vb, athi);
    ogemm_kernel<<<dim3(L_ / 64, 2, B_), 256, 0, stream>>>(
        WoA, athi, b_o, out);
}